// Round 14
// baseline (1690.415 us; speedup 1.0000x reference)
//
#include <hip/hip_runtime.h>
#include <math.h>

#define GLB_PTR(x) ((const __attribute__((address_space(1))) void*)(x))
#define LDS_PTR(x) ((__attribute__((address_space(3))) void*)(x))

typedef __bf16 bf16x8 __attribute__((ext_vector_type(8)));
typedef float  f32x4  __attribute__((ext_vector_type(4)));

// Sizes: B=512, S=8, U=512, D=32, G=8, DIM_IN=4096, DAG=2048
// out layout: att[512*16384] | ga[512*2048] | w[512^3] | outputs[512*16384]
// Fused back half: block (b0,u0) owns its full m-range, so softmax stats are
// block-local. Pass 1: MFMA scores -> masked exp -> Ls (registers only, no
// writes). Pass 2: recompute identical scores, w = exp(s)*IL (masked -> 0),
// write w + PV accumulate -> outs. p never materialized (saves ~1 GB HBM).

// ---------------- K1/K2: per-split fp32 GEMM (64x64 tile, Kstep 16) ----------------
__global__ __launch_bounds__(256) void gemm_split(
    const float* __restrict__ A, int lda, int Ksz,
    const float* __restrict__ Bw, int NS,
    const float* __restrict__ bias,
    float* __restrict__ C, int ldc)
{
  const int n0 = blockIdx.x * 64;
  const int b0 = blockIdx.y * 64;
  const int s  = n0 / NS;
  const float* Bp = Bw + (size_t)s * Ksz * NS;
  const int nloc0 = n0 - s * NS;
  const int acol0 = s * Ksz;

  __shared__ float As[16][64];
  __shared__ float Bs[16][64];

  const int t  = threadIdx.x;
  const int tb = t & 15, tn = t >> 4;
  float acc[4][4] = {};

  for (int k0 = 0; k0 < Ksz; k0 += 16) {
    {
      int r = t & 63, g = t >> 6;
      float4 v = *reinterpret_cast<const float4*>(
          A + (size_t)(b0 + r) * lda + acol0 + k0 + 4 * g);
      As[4*g+0][r] = v.x; As[4*g+1][r] = v.y; As[4*g+2][r] = v.z; As[4*g+3][r] = v.w;
    }
    {
      int kk = t >> 4, n4 = t & 15;
      float4 v = *reinterpret_cast<const float4*>(
          Bp + (size_t)(k0 + kk) * NS + nloc0 + 4 * n4);
      *reinterpret_cast<float4*>(&Bs[kk][4*n4]) = v;
    }
    __syncthreads();
#pragma unroll
    for (int k = 0; k < 16; ++k) {
      float4 a4 = *reinterpret_cast<const float4*>(&As[k][4*tb]);
      float4 b4 = *reinterpret_cast<const float4*>(&Bs[k][4*tn]);
      float av[4] = {a4.x, a4.y, a4.z, a4.w};
      float bv[4] = {b4.x, b4.y, b4.z, b4.w};
#pragma unroll
      for (int i = 0; i < 4; ++i)
#pragma unroll
        for (int j = 0; j < 4; ++j)
          acc[i][j] = fmaf(av[i], bv[j], acc[i][j]);
    }
    __syncthreads();
  }
#pragma unroll
  for (int i = 0; i < 4; ++i) {
    int row = b0 + 4*tb + i;
    int col = n0 + 4*tn;
    float4 o;
    o.x = acc[i][0] + bias[col + 0];
    o.y = acc[i][1] + bias[col + 1];
    o.z = acc[i][2] + bias[col + 2];
    o.w = acc[i][3] + bias[col + 3];
    *reinterpret_cast<float4*>(C + (size_t)row * ldc + col) = o;
  }
}

// MFMA phase for one 16-m chunk (v5-verbatim): 4 u's per wave, split-bf16,
// C -> tr[row*17 + (u ^ ((row>>6)<<2))], row = b*16+m.
__device__ __forceinline__ void mfma_chunk(
    const float* MaL, float* tr,
    const bf16x8 Ahi[4], const bf16x8 Alo[4], int w, int lm, int kb)
{
#pragma unroll
  for (int q = 0; q < 4; ++q) {
    const int uq = 4 * w + q;
    const int s0 = (lm << 7) + (uq << 3) + ((2 * kb)     ^ (lm & 7));
    const int s1 = (lm << 7) + (uq << 3) + ((2 * kb + 1) ^ (lm & 7));
    float4 g0 = *reinterpret_cast<const float4*>(&MaL[s0 * 4]);
    float4 g1 = *reinterpret_cast<const float4*>(&MaL[s1 * 4]);
    float bf[8] = {g0.x, g0.y, g0.z, g0.w, g1.x, g1.y, g1.z, g1.w};
    bf16x8 Bhi, Blo;
#pragma unroll
    for (int j = 0; j < 8; ++j) {
      __bf16 h = (__bf16)bf[j];
      Bhi[j] = h;
      Blo[j] = (__bf16)(bf[j] - (float)h);
    }
    f32x4 a = {0.f, 0.f, 0.f, 0.f};
    a = __builtin_amdgcn_mfma_f32_16x16x32_bf16(Ahi[q], Blo, a, 0, 0, 0);
    a = __builtin_amdgcn_mfma_f32_16x16x32_bf16(Alo[q], Bhi, a, 0, 0, 0);
    a = __builtin_amdgcn_mfma_f32_16x16x32_bf16(Ahi[q], Bhi, a, 0, 0, 0);
#pragma unroll
    for (int i = 0; i < 4; ++i) {
      const int row = (kb * 4 + i) * 16 + lm;
      tr[row * 17 + (uq ^ ((row >> 6) << 2))] = a[i];
    }
  }
}

// ---------------- fused back half ----------------
__global__ __launch_bounds__(256, 3) void fused_back(
    const float* __restrict__ att,   // [512][512][32]
    const float* __restrict__ ma,    // [512][512][32]
    const float* __restrict__ mo,    // [512][512][32]
    const float* __restrict__ rnd,   // [512][512][512]
    const float* __restrict__ temp,  // [512]
    float* __restrict__ wout,        // [512][512][512] final w
    float* __restrict__ outs)        // [512][512][32] outputs
{
  __shared__ float MaL[2048 * 4];    // 32 KB staged ma chunk
  __shared__ float tr[256 * 17];     // 17 KB scores / p tile
  const int b0 = blockIdx.x * 16;
  const int u0 = blockIdx.y * 16;
  const int t  = threadIdx.x;
  const int w  = t >> 6, l = t & 63;
  const int lm = l & 15, kb = l >> 4;      // MFMA decode
  const int eu = t & 15, eb = t >> 4;      // emit decode (u fastest)
  const int gbe = b0 + eb;
  const int pu = t >> 4, bq = (t >> 2) & 3, dh = t & 3;   // PV decode

  const float tmp = temp[u0 + eu];

  // A-fragments (att), split hi/lo bf16, loaded once
  bf16x8 Ahi[4], Alo[4];
#pragma unroll
  for (int q = 0; q < 4; ++q) {
    const float* ap = att + (size_t)(b0 + lm) * 16384
                    + (size_t)(u0 + 4 * w + q) * 32 + kb * 8;
    float4 a0 = *reinterpret_cast<const float4*>(ap);
    float4 a1 = *reinterpret_cast<const float4*>(ap + 4);
    float af[8] = {a0.x, a0.y, a0.z, a0.w, a1.x, a1.y, a1.z, a1.w};
#pragma unroll
    for (int j = 0; j < 8; ++j) {
      __bf16 h = (__bf16)af[j];
      Ahi[q][j] = h;
      Alo[q][j] = (__bf16)(af[j] - (float)h);
    }
  }

  // staging source offsets (slot s = k*256+t holds ma(m, u, d4 ^ (m&7)))
  int off[8];
#pragma unroll
  for (int k = 0; k < 8; ++k) {
    int s = k * 256 + t;
    int mm = s >> 7, uu = (s >> 3) & 15, d4s = s & 7;
    off[k] = mm * 16384 + (u0 + uu) * 32 + ((d4s ^ (mm & 7)) << 2);
  }

  const float* rbase = rnd  + (size_t)gbe * 262144 + u0 + eu;   // + m*512
  float*       wbase = wout + (size_t)gbe * 262144 + u0 + eu;
  const int swz = (eb >> 2) << 2;
  float* trow = &tr[(eb * 16) * 17 + (eu ^ swz)];

  float Ls[8];
#pragma unroll
  for (int g = 0; g < 8; ++g) Ls[g] = 0.f;

  float rc[16], rn[16];

  // ================ pass 1: group sums only ================
#pragma unroll
  for (int k = 0; k < 8; ++k)
    __builtin_amdgcn_global_load_lds(GLB_PTR(ma + (size_t)off[k]),
                                     LDS_PTR(&MaL[(k * 256 + w * 64) * 4]), 16, 0, 0);
#pragma unroll
  for (int j = 0; j < 16; ++j) rc[j] = rbase[(size_t)j * 512];

#pragma unroll 1
  for (int c = 0; c < 32; ++c) {
    const int m0 = c * 16;
    __syncthreads();                 // A: MaL(c) drained; tr free
    mfma_chunk(MaL, tr, Ahi, Alo, w, lm, kb);
    __syncthreads();                 // B: tr ready; MaL reads done
    if (c < 31) {
#pragma unroll
      for (int k = 0; k < 8; ++k)
        __builtin_amdgcn_global_load_lds(
            GLB_PTR(ma + (size_t)off[k] + (size_t)(m0 + 16) * 16384),
            LDS_PTR(&MaL[(k * 256 + w * 64) * 4]), 16, 0, 0);
#pragma unroll
      for (int j = 0; j < 16; ++j)
        rn[j] = rbase[(size_t)(m0 + 16 + j) * 512];
    }
#pragma unroll
    for (int j = 0; j < 16; ++j) {
      const int gm = m0 + j;
      if (!((rc[j] < 0.1f) | (gm == gbe)))
        Ls[j & 7] += __expf(trow[j * 17] * tmp);
    }
#pragma unroll
    for (int j = 0; j < 16; ++j) rc[j] = rn[j];
  }

  float IL[8];
#pragma unroll
  for (int g = 0; g < 8; ++g) IL[g] = 1.0f / (8.0f * Ls[g]);

  // ================ pass 2: w emit + PV ================
  float4 acc[4][2];
#pragma unroll
  for (int i = 0; i < 4; ++i) {
    acc[i][0] = make_float4(0.f, 0.f, 0.f, 0.f);
    acc[i][1] = make_float4(0.f, 0.f, 0.f, 0.f);
  }
#pragma unroll
  for (int k = 0; k < 8; ++k)
    __builtin_amdgcn_global_load_lds(GLB_PTR(ma + (size_t)off[k]),
                                     LDS_PTR(&MaL[(k * 256 + w * 64) * 4]), 16, 0, 0);
#pragma unroll
  for (int j = 0; j < 16; ++j) rc[j] = rbase[(size_t)j * 512];

#pragma unroll 1
  for (int c = 0; c < 32; ++c) {
    const int m0 = c * 16;
    __syncthreads();                 // A: MaL(c) drained; tr free (PV(c-1) done)
    mfma_chunk(MaL, tr, Ahi, Alo, w, lm, kb);   // identical sequence -> same s
    __syncthreads();                 // B: tr scores ready; MaL reads done
    if (c < 31) {
#pragma unroll
      for (int k = 0; k < 8; ++k)
        __builtin_amdgcn_global_load_lds(
            GLB_PTR(ma + (size_t)off[k] + (size_t)(m0 + 16) * 16384),
            LDS_PTR(&MaL[(k * 256 + w * 64) * 4]), 16, 0, 0);
#pragma unroll
      for (int j = 0; j < 16; ++j)
        rn[j] = rbase[(size_t)(m0 + 16 + j) * 512];
    }
    // ---- emit: w = exp(s)*IL (masked -> 0); coalesced w write; p -> tr in place ----
#pragma unroll
    for (int j = 0; j < 16; ++j) {
      const int gm = m0 + j;
      float p;
      if ((rc[j] < 0.1f) | (gm == gbe)) p = 0.f;
      else                              p = __expf(trow[j * 17] * tmp) * IL[j & 7];
      trow[j * 17] = p;
      wbase[(size_t)gm * 512] = p;
    }
#pragma unroll
    for (int j = 0; j < 16; ++j) rc[j] = rn[j];
    __syncthreads();                 // C: tr holds normalized p
    // ---- PV: acc[4b][8d] += p[b][m][pu] * mo[m][pu][d] (mo from L2) ----
#pragma unroll
    for (int m = 0; m < 16; ++m) {
      const float* mop = mo + (size_t)(m0 + m) * 16384
                       + (size_t)(u0 + pu) * 32 + dh * 8;
      float4 v0 = *reinterpret_cast<const float4*>(mop);
      float4 v1 = *reinterpret_cast<const float4*>(mop + 4);
#pragma unroll
      for (int i = 0; i < 4; ++i) {
        float e = tr[((4 * bq + i) * 16 + m) * 17 + (pu ^ (bq << 2))];
        acc[i][0].x = fmaf(e, v0.x, acc[i][0].x);
        acc[i][0].y = fmaf(e, v0.y, acc[i][0].y);
        acc[i][0].z = fmaf(e, v0.z, acc[i][0].z);
        acc[i][0].w = fmaf(e, v0.w, acc[i][0].w);
        acc[i][1].x = fmaf(e, v1.x, acc[i][1].x);
        acc[i][1].y = fmaf(e, v1.y, acc[i][1].y);
        acc[i][1].z = fmaf(e, v1.z, acc[i][1].z);
        acc[i][1].w = fmaf(e, v1.w, acc[i][1].w);
      }
    }
  }

  // epilogue: outputs
#pragma unroll
  for (int i = 0; i < 4; ++i) {
    float* dst = outs + ((size_t)(b0 + 4 * bq + i) * 512 + u0 + pu) * 32 + 8 * dh;
    *reinterpret_cast<float4*>(dst)     = acc[i][0];
    *reinterpret_cast<float4*>(dst + 4) = acc[i][1];
  }
}

extern "C" void kernel_launch(void* const* d_in, const int* in_sizes, int n_in,
                              void* d_out, int out_size, void* d_ws, size_t ws_size,
                              hipStream_t stream) {
  const float* x    = (const float*)d_in[0];   // [512][4096]
  const float* ma   = (const float*)d_in[1];   // [512][512][32]
  const float* mo   = (const float*)d_in[2];   // [512][512][32]
  const float* rnd  = (const float*)d_in[3];   // [512][512][512]
  const float* w1   = (const float*)d_in[4];   // [8][512][256]
  const float* b1   = (const float*)d_in[5];   // [8][256]
  const float* w2   = (const float*)d_in[6];   // [8][256][2048]
  const float* b2   = (const float*)d_in[7];   // [8][2048]
  const float* temp = (const float*)d_in[8];   // [512]

  float* out  = (float*)d_out;
  float* att  = out;                  // 8388608
  float* ga   = out + 8388608;        // 1048576
  float* wbuf = out + 9437184;        // 134217728
  float* outs = out + 143654912;      // 8388608

  gemm_split<<<dim3(32, 8), 256, 0, stream>>>(x, 4096, 512, w1, 256, b1, ga, 2048);
  gemm_split<<<dim3(256, 8), 256, 0, stream>>>(ga, 2048, 256, w2, 2048, b2, att, 16384);
  fused_back<<<dim3(32, 32), 256, 0, stream>>>(att, ma, mo, rnd, temp, wbuf, outs);
}